// Round 1
// baseline (405.473 us; speedup 1.0000x reference)
//
#include <hip/hip_runtime.h>
#include <math.h>

#define L_SEQ 2048
#define H_CH  512
#define N_ST  64

// ---------------------------------------------------------------------------
// Kernel 1: Cauchy generating function -> roots[h][l] (complex)
// roots = c2 * (k00 - k01*k10/(1+k11)),  kXY = sum_n wXY_n / (g_l - lam_n)
// ---------------------------------------------------------------------------
__global__ __launch_bounds__(256)
void s4_cauchy(const float* __restrict__ lam_r_g, const float* __restrict__ lam_i_g,
               const float* __restrict__ p_r_g,  const float* __restrict__ p_i_g,
               const float* __restrict__ b_r_g,  const float* __restrict__ b_i_g,
               const float* __restrict__ c_g,    const float* __restrict__ log_step_g,
               float2* __restrict__ roots)
{
    __shared__ float s_lr[N_ST], s_li[N_ST];
    __shared__ float s_w00r[N_ST], s_w00i[N_ST];
    __shared__ float s_w01r[N_ST], s_w01i[N_ST];
    __shared__ float s_w10r[N_ST], s_w10i[N_ST];
    __shared__ float s_w11[N_ST];

    const int h   = blockIdx.y;
    const int l   = blockIdx.x * 256 + threadIdx.x;
    const int tid = threadIdx.x;

    if (tid < N_ST) {
        const int idx = h * N_ST + tid;
        s_lr[tid] = fminf(lam_r_g[idx], -0.0001f);   // clip(lambda_real, max=-1e-4)
        s_li[tid] = lam_i_g[idx];
        const float pr = p_r_g[idx], pi = p_i_g[idx];
        const float br = b_r_g[idx], bi = b_i_g[idx];
        const float c0 = c_g[idx * 2 + 0], c1 = c_g[idx * 2 + 1];
        // cc = conj(c0 + i c1) = (c0, -c1); qc = conj(pc) = (pr, -pi)
        s_w00r[tid] = c0 * br + c1 * bi;  s_w00i[tid] = c0 * bi - c1 * br;  // cc*bc
        s_w01r[tid] = c0 * pr + c1 * pi;  s_w01i[tid] = c0 * pi - c1 * pr;  // cc*pc
        s_w10r[tid] = pr * br + pi * bi;  s_w10i[tid] = pr * bi - pi * br;  // qc*bc
        s_w11[tid]  = pr * pr + pi * pi;                                    // qc*pc (real)
    }
    __syncthreads();

    const float step = expf(log_step_g[h]);
    const float ts   = 2.0f / step;

    // omega_l = exp(-2*pi*i * l / L), angle rounded in fp32 like jnp complex64
    const float ang = -6.2831853071795864769f * ((float)l * (1.0f / (float)L_SEQ));
    float wi, wr;
    sincosf(ang, &wi, &wr);              // omega = (wr, wi)

    const float dr = 1.0f + wr, di = wi;            // 1 + omega
    const float dinv = 1.0f / (dr * dr + di * di);
    const float nr = 1.0f - wr, ni = -wi;           // 1 - omega
    const float gr = ts * (nr * dr + ni * di) * dinv;   // g = (2/step)(1-w)/(1+w)
    const float gi = ts * (ni * dr - nr * di) * dinv;
    const float c2r = 2.0f * dr * dinv;             // c2 = 2/(1+omega)
    const float c2i = -2.0f * di * dinv;

    float k00r = 0.f, k00i = 0.f, k01r = 0.f, k01i = 0.f;
    float k10r = 0.f, k10i = 0.f, k11r = 0.f, k11i = 0.f;
#pragma unroll 8
    for (int n = 0; n < N_ST; ++n) {
        const float ddr = gr - s_lr[n];
        const float ddi = gi - s_li[n];
        const float rinv = 1.0f / (ddr * ddr + ddi * ddi);
        const float rr = ddr * rinv;    // Re 1/(g-lam)
        const float ri = -ddi * rinv;   // Im 1/(g-lam)
        k00r += s_w00r[n] * rr - s_w00i[n] * ri;  k00i += s_w00r[n] * ri + s_w00i[n] * rr;
        k01r += s_w01r[n] * rr - s_w01i[n] * ri;  k01i += s_w01r[n] * ri + s_w01i[n] * rr;
        k10r += s_w10r[n] * rr - s_w10i[n] * ri;  k10i += s_w10r[n] * ri + s_w10i[n] * rr;
        k11r += s_w11[n] * rr;                    k11i += s_w11[n] * ri;
    }

    // q = (k01*k10)/(1+k11)
    const float qdr = 1.0f + k11r, qdi = k11i;
    const float qinv = 1.0f / (qdr * qdr + qdi * qdi);
    const float pnr = k01r * k10r - k01i * k10i;
    const float pni = k01r * k10i + k01i * k10r;
    const float qr = (pnr * qdr + pni * qdi) * qinv;
    const float qi = (pni * qdr - pnr * qdi) * qinv;
    const float rr0 = k00r - qr;
    const float ri0 = k00i - qi;
    roots[h * L_SEQ + l] = make_float2(c2r * rr0 - c2i * ri0,
                                       c2r * ri0 + c2i * rr0);
}

// ---------------------------------------------------------------------------
// Kernel 2: kern[h][s] = Re(ifft(roots[h]))[s]
// Uses m <-> L-m pairing:  kern[s] = (1/L)[rr0 + (-1)^s rrN2
//                               + sum_{m=1}^{1023} A_m cos(2pi m s/L) - B_m sin(...)]
// and computes s and s+1024 together ((-1)^m sign flip on the same twiddles).
// Twiddles advance by a per-thread rotation recurrence (no table, no conflicts).
// ---------------------------------------------------------------------------
__global__ __launch_bounds__(256)
void s4_idft(const float2* __restrict__ roots, float* __restrict__ kern)
{
    __shared__ float2 sAB[1024];   // sAB[0] = (rr0, rrN2); sAB[m] = (A_m, B_m)
    const int h   = blockIdx.y;
    const int tid = threadIdx.x;
    const int s   = blockIdx.x * 256 + tid;          // s in [0, 1024)
    const float2* __restrict__ row = roots + h * L_SEQ;

    for (int m = tid; m < 1024; m += 256) {
        if (m == 0) {
            sAB[0] = make_float2(row[0].x, row[1024].x);
        } else {
            const float2 a = row[m];
            const float2 b = row[L_SEQ - m];
            sAB[m] = make_float2(a.x + b.x, a.y - b.y);   // A_m, B_m
        }
    }
    __syncthreads();

    float co, si;
    sincosf((float)s * (6.2831853071795864769f / (float)L_SEQ), &si, &co);
    float cr = co, ci = si;          // e^{i theta * m}, starting at m = 1

    const float2 ab0 = sAB[0];
    const float base = ab0.x + ((s & 1) ? -ab0.y : ab0.y);
    float accA = base;   // for kern[s]
    float accB = base;   // for kern[s + 1024]

    int m = 1;
    for (; m + 1 < 1024; m += 2) {
        // m odd: contributes +t to accA, -t to accB
        float2 ab = sAB[m];
        float t = ab.x * cr - ab.y * ci;
        accA += t; accB -= t;
        float tr = cr * co - ci * si;  ci = cr * si + ci * co;  cr = tr;
        // m+1 even: contributes +t to both
        ab = sAB[m + 1];
        t = ab.x * cr - ab.y * ci;
        accA += t; accB += t;
        tr = cr * co - ci * si;  ci = cr * si + ci * co;  cr = tr;
    }
    {   // leftover m = 1023 (odd)
        const float2 ab = sAB[1023];
        const float t = ab.x * cr - ab.y * ci;
        accA += t; accB -= t;
    }

    kern[h * L_SEQ + s]        = accA * (1.0f / (float)L_SEQ);
    kern[h * L_SEQ + s + 1024] = accB * (1.0f / (float)L_SEQ);
}

// ---------------------------------------------------------------------------
// Kernel 3: causal convolution  out[t][h] = sum_{s<=t} kern[h][s] u[t-s][h] + d[h] u[t][h]
// ---------------------------------------------------------------------------
__global__ __launch_bounds__(256)
void s4_conv(const float* __restrict__ kern, const float* __restrict__ u,
             const float* __restrict__ dvec, float* __restrict__ out)
{
    __shared__ float sk[L_SEQ];
    __shared__ float su[L_SEQ];
    const int h   = blockIdx.y;
    const int tid = threadIdx.x;
    const int t0  = blockIdx.x * 256;
    const int t   = t0 + tid;
    const int lim = t0 + 256;     // only indices <= t0+255 are ever read

    for (int j = tid; j < lim; j += 256) {
        sk[j] = kern[h * L_SEQ + j];
        su[j] = u[j * H_CH + h];
    }
    __syncthreads();

    float acc = 0.0f;
#pragma unroll 4
    for (int s = 0; s <= t; ++s)
        acc = fmaf(sk[s], su[t - s], acc);

    out[t * H_CH + h] = acc + dvec[h] * su[tid + t0];
}

// ---------------------------------------------------------------------------
extern "C" void kernel_launch(void* const* d_in, const int* in_sizes, int n_in,
                              void* d_out, int out_size, void* d_ws, size_t ws_size,
                              hipStream_t stream)
{
    const float* u        = (const float*)d_in[0];
    const float* lam_r    = (const float*)d_in[1];
    const float* lam_i    = (const float*)d_in[2];
    const float* p_r      = (const float*)d_in[3];
    const float* p_i      = (const float*)d_in[4];
    const float* b_r      = (const float*)d_in[5];
    const float* b_i      = (const float*)d_in[6];
    const float* cmat     = (const float*)d_in[7];
    const float* dvec     = (const float*)d_in[8];
    const float* log_step = (const float*)d_in[9];
    float* out = (float*)d_out;

    float2* roots = (float2*)d_ws;                                   // 8 MB
    float*  kern  = (float*)((char*)d_ws +
                             (size_t)H_CH * L_SEQ * sizeof(float2)); // +4 MB

    s4_cauchy<<<dim3(L_SEQ / 256, H_CH), dim3(256), 0, stream>>>(
        lam_r, lam_i, p_r, p_i, b_r, b_i, cmat, log_step, roots);
    s4_idft<<<dim3(1024 / 256, H_CH), dim3(256), 0, stream>>>(roots, kern);
    s4_conv<<<dim3(L_SEQ / 256, H_CH), dim3(256), 0, stream>>>(kern, u, dvec, out);
}

// Round 5
// 207.022 us; speedup vs baseline: 1.9586x; 1.9586x over previous
//
#include <hip/hip_runtime.h>
#include <math.h>

#define L_SEQ 2048
#define H_CH  512
#define N_ST  64

__device__ __forceinline__ float frcp(float x) { return __builtin_amdgcn_rcpf(x); }
__device__ __forceinline__ int swz(int i) { return i ^ (((i >> 5) & 7) << 2); }

// ---------------------------------------------------------------------------
// Kernel 0: precompute per-(h,n) Cauchy weights into global scratch.
// Wa = {lam_r_clipped, lam_i, w00r, w00i}; Wb = {w01r, w01i, w10r, w10i}; Wc = w11
// ---------------------------------------------------------------------------
__global__ __launch_bounds__(256)
void s4_prep(const float* __restrict__ lam_r_g, const float* __restrict__ lam_i_g,
             const float* __restrict__ p_r_g,  const float* __restrict__ p_i_g,
             const float* __restrict__ b_r_g,  const float* __restrict__ b_i_g,
             const float* __restrict__ c_g,
             float4* __restrict__ Wa, float4* __restrict__ Wb, float* __restrict__ Wc)
{
    const int g = blockIdx.x * 256 + threadIdx.x;      // [0, 512*64)
    const float lr = fminf(lam_r_g[g], -0.0001f);
    const float li = lam_i_g[g];
    const float pr = p_r_g[g], pi = p_i_g[g];
    const float br = b_r_g[g], bi = b_i_g[g];
    const float c0 = c_g[2 * g], c1 = c_g[2 * g + 1];
    Wa[g] = make_float4(lr, li, c0 * br + c1 * bi, c0 * bi - c1 * br);
    Wb[g] = make_float4(c0 * pr + c1 * pi, c0 * pi - c1 * pr,
                        pr * br + pi * bi, pr * bi - pi * br);
    Wc[g] = pr * pr + pi * pi;
}

// ---------------------------------------------------------------------------
// Kernel 1: Cauchy generating function -> roots[h][l] (complex)
// ---------------------------------------------------------------------------
__global__ __launch_bounds__(256)
void s4_cauchy(const float4* __restrict__ Wa, const float4* __restrict__ Wb,
               const float* __restrict__ Wc, const float* __restrict__ log_step_g,
               float2* __restrict__ roots)
{
    const int h = blockIdx.y;
    const int l = blockIdx.x * 256 + threadIdx.x;

    const float step = expf(log_step_g[h]);
    const float ts   = 2.0f / step;

    const float ang = -6.2831853071795864769f * ((float)l * (1.0f / (float)L_SEQ));
    float wi, wr;
    sincosf(ang, &wi, &wr);                      // omega = (wr, wi)

    const float dr = 1.0f + wr, di = wi;         // 1 + omega
    const float dinv = frcp(dr * dr + di * di);
    const float nr = 1.0f - wr, ni = -wi;        // 1 - omega
    const float gr = ts * (nr * dr + ni * di) * dinv;
    const float gi = ts * (ni * dr - nr * di) * dinv;
    const float c2r = 2.0f * dr * dinv;
    const float c2i = -2.0f * di * dinv;

    const float4* __restrict__ wa = Wa + h * N_ST;
    const float4* __restrict__ wb = Wb + h * N_ST;
    const float*  __restrict__ wc = Wc + h * N_ST;

    float k00r = 0.f, k00i = 0.f, k01r = 0.f, k01i = 0.f;
    float k10r = 0.f, k10i = 0.f, k11r = 0.f, k11i = 0.f;
#pragma unroll 4
    for (int n = 0; n < N_ST; ++n) {
        const float4 A = wa[n];
        const float4 B = wb[n];
        const float w11 = wc[n];
        const float ddr = gr - A.x;
        const float ddi = gi - A.y;
        const float rinv = frcp(fmaf(ddr, ddr, ddi * ddi));
        const float rr = ddr * rinv;
        const float ri = -ddi * rinv;
        k00r = fmaf(A.z, rr, fmaf(-A.w, ri, k00r));
        k00i = fmaf(A.z, ri, fmaf( A.w, rr, k00i));
        k01r = fmaf(B.x, rr, fmaf(-B.y, ri, k01r));
        k01i = fmaf(B.x, ri, fmaf( B.y, rr, k01i));
        k10r = fmaf(B.z, rr, fmaf(-B.w, ri, k10r));
        k10i = fmaf(B.z, ri, fmaf( B.w, rr, k10i));
        k11r = fmaf(w11, rr, k11r);
        k11i = fmaf(w11, ri, k11i);
    }

    const float qdr = 1.0f + k11r, qdi = k11i;
    const float qinv = frcp(qdr * qdr + qdi * qdi);
    const float pnr = k01r * k10r - k01i * k10i;
    const float pni = k01r * k10i + k01i * k10r;
    const float qr = (pnr * qdr + pni * qdi) * qinv;
    const float qi = (pni * qdr - pnr * qdi) * qinv;
    const float rr0 = k00r - qr;
    const float ri0 = k00i - qi;
    roots[h * L_SEQ + l] = make_float2(c2r * rr0 - c2i * ri0,
                                       c2r * ri0 + c2i * rr0);
}

// ---------------------------------------------------------------------------
// Kernel 2: pair spectrum: X[h][m] = (A_m, B_m); X[h][0] = (roots0.re, roots1024.re)
// ---------------------------------------------------------------------------
__global__ __launch_bounds__(256)
void s4_pair(const float2* __restrict__ roots, float2* __restrict__ X)
{
    const int h = blockIdx.y;
    const int m = blockIdx.x * 256 + threadIdx.x;    // [0,1024)
    const float2* __restrict__ row = roots + h * L_SEQ;
    float2 x;
    if (m == 0) {
        x = make_float2(row[0].x, row[1024].x);
    } else {
        const float2 a = row[m];
        const float2 b = row[L_SEQ - m];
        x = make_float2(a.x + b.x, a.y - b.y);
    }
    X[h * 1024 + m] = x;
}

// ---------------------------------------------------------------------------
// Kernel 3: kern[h][s], kern[h][s+1024] via 4-strand Horner in z^4.
// kern[s]*L = X0.x + (-1)^s X0.y + Re(sum_{m=1}^{1023} X_m z^m),  z = e^{2pi i s/L}
// Strand c holds S_c = sum_j X_{4j+c} (z^4)^{power}; final combine applies z^c.
// NOTE: strand 0's Horner ends at j=1 (m=0 excluded), leaving
//       s0 = sum_{j=1..255} X_{4j} (z^4)^{j-1}; the final combine's z4*s0
//       supplies the remaining z^4 exactly once (double-apply was the R4 bug).
// ---------------------------------------------------------------------------
__global__ __launch_bounds__(256)
void s4_idft(const float2* __restrict__ X, float* __restrict__ kern)
{
    const int h = blockIdx.y;
    const int s = blockIdx.x * 256 + threadIdx.x;    // [0,1024)
    const float4* __restrict__ Xr = (const float4*)(X + h * 1024); // Xr[j]=(X_{2j},X_{2j+1})

    const float th = (float)s * (6.2831853071795864769f / (float)L_SEQ);
    float zi, zr;
    sincosf(th, &zi, &zr);                           // z = (zr, zi)
    const float z2r = zr * zr - zi * zi, z2i = 2.0f * zr * zi;
    const float z4r = z2r * z2r - z2i * z2i, z4i = 2.0f * z2r * z2i;

    // init strands from j=255: X_{1020..1023}
    float4 a = Xr[510], b = Xr[511];
    float s0r = a.x, s0i = a.y, s1r = a.z, s1i = a.w;
    float s2r = b.x, s2i = b.y, s3r = b.z, s3i = b.w;

#pragma unroll 2
    for (int j = 254; j >= 1; --j) {
        a = Xr[2 * j];
        b = Xr[2 * j + 1];
        float t;
        t   = fmaf(s0r, z4r, fmaf(-s0i, z4i, a.x));
        s0i = fmaf(s0r, z4i, fmaf( s0i, z4r, a.y));  s0r = t;
        t   = fmaf(s1r, z4r, fmaf(-s1i, z4i, a.z));
        s1i = fmaf(s1r, z4i, fmaf( s1i, z4r, a.w));  s1r = t;
        t   = fmaf(s2r, z4r, fmaf(-s2i, z4i, b.x));
        s2i = fmaf(s2r, z4i, fmaf( s2i, z4r, b.y));  s2r = t;
        t   = fmaf(s3r, z4r, fmaf(-s3i, z4i, b.z));
        s3i = fmaf(s3r, z4i, fmaf( s3i, z4r, b.w));  s3r = t;
    }
    // j = 0: s0 untouched (its z^4 comes from the final combine);
    // s1..s3 do the last Horner step adding X1..X3.
    a = Xr[0];   // (X0r, X0i, X1r, X1i) — X0 = (rr0, rrN2) special
    b = Xr[1];   // (X2, X3)
    {
        float t;
        t   = fmaf(s1r, z4r, fmaf(-s1i, z4i, a.z));
        s1i = fmaf(s1r, z4i, fmaf( s1i, z4r, a.w));  s1r = t;
        t   = fmaf(s2r, z4r, fmaf(-s2i, z4i, b.x));
        s2i = fmaf(s2r, z4i, fmaf( s2i, z4r, b.y));  s2r = t;
        t   = fmaf(s3r, z4r, fmaf(-s3i, z4i, b.z));
        s3i = fmaf(s3r, z4i, fmaf( s3i, z4r, b.w));  s3r = t;
    }

    const float base = a.x + ((s & 1) ? -a.y : a.y);
    const float z3r = z2r * zr - z2i * zi;
    const float z3i = z2r * zi + z2i * zr;
    const float P = (z2r * s2r - z2i * s2i) + (z4r * s0r - z4i * s0i); // even m
    const float Q = (zr  * s1r - zi  * s1i) + (z3r * s3r - z3i * s3i); // odd m
    const float inv = 1.0f / (float)L_SEQ;
    kern[h * L_SEQ + s]        = (base + P + Q) * inv;
    kern[h * L_SEQ + s + 1024] = (base + P - Q) * inv;
}

// ---------------------------------------------------------------------------
// Kernel 4: causal conv. Block (q,h): 128 threads, 8 consecutive outputs each.
// Register sliding window (16 su values), 8-tap chunks, kern taps from global
// (uniform, L1/scalar cache), su in swizzled LDS.
// ---------------------------------------------------------------------------
__global__ __launch_bounds__(128)
void s4_conv(const float* __restrict__ kern, const float* __restrict__ u,
             const float* __restrict__ dvec, float* __restrict__ out)
{
    __shared__ __align__(16) float su[4128];  // logical: su[i] = u[i-2055], zero below
    const int h   = blockIdx.y;
    const int q   = blockIdx.x;               // 0: t in [0,1024); 1: t in [1024,2048)
    const int tid = threadIdx.x;              // [0,128)
    const int t_lo  = q * 1024 + tid * 8;
    const int n_u   = (q + 1) * 1024;         // u values needed
    const int s_end = (q + 1) * 1024;         // tap range needed

    for (int i = tid; i < 4128; i += 128) su[swz(i)] = 0.0f;
    __syncthreads();
    for (int j = tid; j < n_u; j += 128) su[swz(2055 + j)] = u[j * H_CH + h];
    __syncthreads();

    const float* __restrict__ kr = kern + h * L_SEQ;

    float ac[8];
#pragma unroll
    for (int r = 0; r < 8; ++r) ac[r] = 0.0f;

    int W = t_lo + 2048;                       // window base (logical su index)
    float4 hi0 = *(const float4*)(su + swz(W + 8));
    float4 hi1 = *(const float4*)(su + swz(W + 12));
    float4 lo0 = *(const float4*)(su + swz(W));
    float4 lo1 = *(const float4*)(su + swz(W + 4));
    float4 k0  = *(const float4*)(kr);
    float4 k1  = *(const float4*)(kr + 4);

    for (int s = 0; s < s_end; s += 8) {
        // prefetch next chunk
        const int Wn = W - 8;
        const float4 nlo0 = *(const float4*)(su + swz(Wn));
        const float4 nlo1 = *(const float4*)(su + swz(Wn + 4));
        const int sn = (s + 8 < s_end) ? s + 8 : 0;
        const float4 nk0 = *(const float4*)(kr + sn);
        const float4 nk1 = *(const float4*)(kr + sn + 4);

        const float w[16] = {lo0.x, lo0.y, lo0.z, lo0.w,
                             lo1.x, lo1.y, lo1.z, lo1.w,
                             hi0.x, hi0.y, hi0.z, hi0.w,
                             hi1.x, hi1.y, hi1.z, hi1.w};
        const float kk[8] = {k0.x, k0.y, k0.z, k0.w, k1.x, k1.y, k1.z, k1.w};
#pragma unroll
        for (int d = 0; d < 8; ++d)
#pragma unroll
            for (int r = 0; r < 8; ++r)
                ac[r] = fmaf(kk[d], w[7 + r - d], ac[r]);

        hi0 = lo0; hi1 = lo1;
        lo0 = nlo0; lo1 = nlo1;
        k0 = nk0; k1 = nk1;
        W = Wn;
    }

    const float dh = dvec[h];
#pragma unroll
    for (int r = 0; r < 8; ++r) {
        const int t = t_lo + r;
        const float ut = su[swz(t + 2055)];
        out[t * H_CH + h] = fmaf(dh, ut, ac[r]);
    }
}

// ---------------------------------------------------------------------------
extern "C" void kernel_launch(void* const* d_in, const int* in_sizes, int n_in,
                              void* d_out, int out_size, void* d_ws, size_t ws_size,
                              hipStream_t stream)
{
    const float* u        = (const float*)d_in[0];
    const float* lam_r    = (const float*)d_in[1];
    const float* lam_i    = (const float*)d_in[2];
    const float* p_r      = (const float*)d_in[3];
    const float* p_i      = (const float*)d_in[4];
    const float* b_r      = (const float*)d_in[5];
    const float* b_i      = (const float*)d_in[6];
    const float* cmat     = (const float*)d_in[7];
    const float* dvec     = (const float*)d_in[8];
    const float* log_step = (const float*)d_in[9];
    float* out = (float*)d_out;

    char* ws = (char*)d_ws;
    float2* roots = (float2*)ws;                              // 8 MB @ 0
    float*  kern  = (float*)ws;                               // 4 MB @ 0 (reuses roots)
    float2* X     = (float2*)(ws + (size_t)8 * 1024 * 1024);  // 4 MB @ 8M
    float4* Wa    = (float4*)(ws + (size_t)12 * 1024 * 1024); // 512 KB
    float4* Wb    = (float4*)(ws + (size_t)12 * 1024 * 1024 + 512 * 1024);
    float*  Wc    = (float*) (ws + (size_t)13 * 1024 * 1024); // 128 KB

    s4_prep<<<dim3(H_CH * N_ST / 256), dim3(256), 0, stream>>>(
        lam_r, lam_i, p_r, p_i, b_r, b_i, cmat, Wa, Wb, Wc);
    s4_cauchy<<<dim3(L_SEQ / 256, H_CH), dim3(256), 0, stream>>>(
        Wa, Wb, Wc, log_step, roots);
    s4_pair<<<dim3(1024 / 256, H_CH), dim3(256), 0, stream>>>(roots, X);
    s4_idft<<<dim3(1024 / 256, H_CH), dim3(256), 0, stream>>>(X, kern);
    s4_conv<<<dim3(2, H_CH), dim3(128), 0, stream>>>(kern, u, dvec, out);
}

// Round 6
// 179.972 us; speedup vs baseline: 2.2530x; 1.1503x over previous
//
#include <hip/hip_runtime.h>
#include <math.h>

#define L_SEQ 2048
#define H_CH  512
#define N_ST  64

__device__ __forceinline__ float frcp(float x) { return __builtin_amdgcn_rcpf(x); }
// Quad-granular LDS pad: +4 floats every 16. Keeps 16B alignment of 4-aligned
// quads, and for 8-aligned window bases the lane->bank map is a tid-shift of a
// uniform pattern => conflict-free for EVERY slide offset (unlike XOR swizzle).
#define PP(i) ((i) + (((i) >> 4) << 2))

// ---------------------------------------------------------------------------
// Kernel 0: precompute per-(h,n) Cauchy weights into global scratch.
// Wa = {lam_r_clipped, lam_i, w00r, w00i}; Wb = {w01r, w01i, w10r, w10i}; Wc = w11
// ---------------------------------------------------------------------------
__global__ __launch_bounds__(256)
void s4_prep(const float* __restrict__ lam_r_g, const float* __restrict__ lam_i_g,
             const float* __restrict__ p_r_g,  const float* __restrict__ p_i_g,
             const float* __restrict__ b_r_g,  const float* __restrict__ b_i_g,
             const float* __restrict__ c_g,
             float4* __restrict__ Wa, float4* __restrict__ Wb, float* __restrict__ Wc)
{
    const int g = blockIdx.x * 256 + threadIdx.x;      // [0, 512*64)
    const float lr = fminf(lam_r_g[g], -0.0001f);
    const float li = lam_i_g[g];
    const float pr = p_r_g[g], pi = p_i_g[g];
    const float br = b_r_g[g], bi = b_i_g[g];
    const float c0 = c_g[2 * g], c1 = c_g[2 * g + 1];
    Wa[g] = make_float4(lr, li, c0 * br + c1 * bi, c0 * bi - c1 * br);
    Wb[g] = make_float4(c0 * pr + c1 * pi, c0 * pi - c1 * pr,
                        pr * br + pi * bi, pr * bi - pi * br);
    Wc[g] = pr * pr + pi * pi;
}

// ---------------------------------------------------------------------------
// Kernel 1: Cauchy generating function -> roots[h][l] (complex)
// ---------------------------------------------------------------------------
__global__ __launch_bounds__(256)
void s4_cauchy(const float4* __restrict__ Wa, const float4* __restrict__ Wb,
               const float* __restrict__ Wc, const float* __restrict__ log_step_g,
               float2* __restrict__ roots)
{
    const int h = blockIdx.y;
    const int l = blockIdx.x * 256 + threadIdx.x;

    const float step = expf(log_step_g[h]);
    const float ts   = 2.0f / step;

    const float ang = -6.2831853071795864769f * ((float)l * (1.0f / (float)L_SEQ));
    float wi, wr;
    sincosf(ang, &wi, &wr);                      // omega = (wr, wi)

    const float dr = 1.0f + wr, di = wi;         // 1 + omega
    const float dinv = frcp(dr * dr + di * di);
    const float nr = 1.0f - wr, ni = -wi;        // 1 - omega
    const float gr = ts * (nr * dr + ni * di) * dinv;
    const float gi = ts * (ni * dr - nr * di) * dinv;
    const float c2r = 2.0f * dr * dinv;
    const float c2i = -2.0f * di * dinv;

    const float4* __restrict__ wa = Wa + h * N_ST;
    const float4* __restrict__ wb = Wb + h * N_ST;
    const float*  __restrict__ wc = Wc + h * N_ST;

    float k00r = 0.f, k00i = 0.f, k01r = 0.f, k01i = 0.f;
    float k10r = 0.f, k10i = 0.f, k11r = 0.f, k11i = 0.f;
#pragma unroll 4
    for (int n = 0; n < N_ST; ++n) {
        const float4 A = wa[n];
        const float4 B = wb[n];
        const float w11 = wc[n];
        const float ddr = gr - A.x;
        const float ddi = gi - A.y;
        const float rinv = frcp(fmaf(ddr, ddr, ddi * ddi));
        const float rr = ddr * rinv;
        const float ri = -ddi * rinv;
        k00r = fmaf(A.z, rr, fmaf(-A.w, ri, k00r));
        k00i = fmaf(A.z, ri, fmaf( A.w, rr, k00i));
        k01r = fmaf(B.x, rr, fmaf(-B.y, ri, k01r));
        k01i = fmaf(B.x, ri, fmaf( B.y, rr, k01i));
        k10r = fmaf(B.z, rr, fmaf(-B.w, ri, k10r));
        k10i = fmaf(B.z, ri, fmaf( B.w, rr, k10i));
        k11r = fmaf(w11, rr, k11r);
        k11i = fmaf(w11, ri, k11i);
    }

    const float qdr = 1.0f + k11r, qdi = k11i;
    const float qinv = frcp(qdr * qdr + qdi * qdi);
    const float pnr = k01r * k10r - k01i * k10i;
    const float pni = k01r * k10i + k01i * k10r;
    const float qr = (pnr * qdr + pni * qdi) * qinv;
    const float qi = (pni * qdr - pnr * qdi) * qinv;
    const float rr0 = k00r - qr;
    const float ri0 = k00i - qi;
    roots[h * L_SEQ + l] = make_float2(c2r * rr0 - c2i * ri0,
                                       c2r * ri0 + c2i * rr0);
}

// ---------------------------------------------------------------------------
// Kernel 2: pair spectrum: X[h][m] = (A_m, B_m); X[h][0] = (roots0.re, roots1024.re)
// ---------------------------------------------------------------------------
__global__ __launch_bounds__(256)
void s4_pair(const float2* __restrict__ roots, float2* __restrict__ X)
{
    const int h = blockIdx.y;
    const int m = blockIdx.x * 256 + threadIdx.x;    // [0,1024)
    const float2* __restrict__ row = roots + h * L_SEQ;
    float2 x;
    if (m == 0) {
        x = make_float2(row[0].x, row[1024].x);
    } else {
        const float2 a = row[m];
        const float2 b = row[L_SEQ - m];
        x = make_float2(a.x + b.x, a.y - b.y);
    }
    X[h * 1024 + m] = x;
}

// ---------------------------------------------------------------------------
// Kernel 3: kern[h][s], kern[h][s+1024] via 4-strand Horner in z^4.
// kern[s]*L = X0.x + (-1)^s X0.y + Re(sum_{m=1}^{1023} X_m z^m),  z = e^{2pi i s/L}
// Strand 0's Horner ends at j=1 (m=0 excluded); the final z4*s0 supplies the
// last z^4 exactly once.
// ---------------------------------------------------------------------------
__global__ __launch_bounds__(256)
void s4_idft(const float2* __restrict__ X, float* __restrict__ kern)
{
    const int h = blockIdx.y;
    const int s = blockIdx.x * 256 + threadIdx.x;    // [0,1024)
    const float4* __restrict__ Xr = (const float4*)(X + h * 1024); // Xr[j]=(X_{2j},X_{2j+1})

    const float th = (float)s * (6.2831853071795864769f / (float)L_SEQ);
    float zi, zr;
    sincosf(th, &zi, &zr);                           // z = (zr, zi)
    const float z2r = zr * zr - zi * zi, z2i = 2.0f * zr * zi;
    const float z4r = z2r * z2r - z2i * z2i, z4i = 2.0f * z2r * z2i;

    // init strands from j=255: X_{1020..1023}
    float4 a = Xr[510], b = Xr[511];
    float s0r = a.x, s0i = a.y, s1r = a.z, s1i = a.w;
    float s2r = b.x, s2i = b.y, s3r = b.z, s3i = b.w;

#pragma unroll 2
    for (int j = 254; j >= 1; --j) {
        a = Xr[2 * j];
        b = Xr[2 * j + 1];
        float t;
        t   = fmaf(s0r, z4r, fmaf(-s0i, z4i, a.x));
        s0i = fmaf(s0r, z4i, fmaf( s0i, z4r, a.y));  s0r = t;
        t   = fmaf(s1r, z4r, fmaf(-s1i, z4i, a.z));
        s1i = fmaf(s1r, z4i, fmaf( s1i, z4r, a.w));  s1r = t;
        t   = fmaf(s2r, z4r, fmaf(-s2i, z4i, b.x));
        s2i = fmaf(s2r, z4i, fmaf( s2i, z4r, b.y));  s2r = t;
        t   = fmaf(s3r, z4r, fmaf(-s3i, z4i, b.z));
        s3i = fmaf(s3r, z4i, fmaf( s3i, z4r, b.w));  s3r = t;
    }
    // j = 0: s0 untouched; s1..s3 do the last Horner step adding X1..X3.
    a = Xr[0];   // (X0r, X0i, X1r, X1i) — X0 = (rr0, rrN2) special
    b = Xr[1];   // (X2, X3)
    {
        float t;
        t   = fmaf(s1r, z4r, fmaf(-s1i, z4i, a.z));
        s1i = fmaf(s1r, z4i, fmaf( s1i, z4r, a.w));  s1r = t;
        t   = fmaf(s2r, z4r, fmaf(-s2i, z4i, b.x));
        s2i = fmaf(s2r, z4i, fmaf( s2i, z4r, b.y));  s2r = t;
        t   = fmaf(s3r, z4r, fmaf(-s3i, z4i, b.z));
        s3i = fmaf(s3r, z4i, fmaf( s3i, z4r, b.w));  s3r = t;
    }

    const float base = a.x + ((s & 1) ? -a.y : a.y);
    const float z3r = z2r * zr - z2i * zi;
    const float z3i = z2r * zi + z2i * zr;
    const float P = (z2r * s2r - z2i * s2i) + (z4r * s0r - z4i * s0i); // even m
    const float Q = (zr  * s1r - zi  * s1i) + (z3r * s3r - z3i * s3i); // odd m
    const float inv = 1.0f / (float)L_SEQ;
    kern[h * L_SEQ + s]        = (base + P + Q) * inv;
    kern[h * L_SEQ + s + 1024] = (base + P - Q) * inv;
}

// ---------------------------------------------------------------------------
// Kernel 4: causal conv, 3 identical-shape block classes per h:
//  cls0: outs [0,1024),    taps [0,1024)     -> out (+ d*u)   (exact, padded)
//  cls1: outs [1024,2048), taps [0,1024)     -> P1 (partial)
//  cls2: outs [1024,2048), taps [1024,2048)  -> P2 (partial, padded)
// 128 thr, 8 outs/thread; window W = tid*8 - sl + 1024 (8-aligned always).
// ---------------------------------------------------------------------------
__global__ __launch_bounds__(128)
void s4_conv(const float* __restrict__ kern, const float* __restrict__ u,
             const float* __restrict__ dvec, float* __restrict__ out,
             float* __restrict__ P1, float* __restrict__ P2)
{
    __shared__ __align__(16) float su[2576];   // PP(2055)=2567 max
    const int cls = blockIdx.x;                // 0,1,2
    const int h   = blockIdx.y;
    const int tid = threadIdx.x;               // [0,128)
    const int tl  = tid * 8;                   // local output base

    for (int i = tid; i < 2576; i += 128) su[i] = 0.0f;
    __syncthreads();
    if (cls == 1) {
        for (int j = tid; j < 2048; j += 128) su[PP(7 + j)] = u[j * H_CH + h];
    } else {
        for (int j = tid; j < 1024; j += 128) su[PP(1031 + j)] = u[j * H_CH + h];
    }
    __syncthreads();

    const float* __restrict__ kr = kern + h * L_SEQ + (cls == 2 ? 1024 : 0);

    float ac[8];
#pragma unroll
    for (int r = 0; r < 8; ++r) ac[r] = 0.0f;

    int W = tl + 1024;                         // logical window base (sl=0)
    int bh = PP(W + 8), bl = PP(W);
    float4 hi0 = *(const float4*)(su + bh);
    float4 hi1 = *(const float4*)(su + bh + 4);
    float4 lo0 = *(const float4*)(su + bl);
    float4 lo1 = *(const float4*)(su + bl + 4);
    float4 k0  = *(const float4*)(kr);
    float4 k1  = *(const float4*)(kr + 4);

    for (int sl = 0; sl < 1024; sl += 8) {
        const int Wn = W - 8;
        const int bn = PP(Wn);
        const float4 nlo0 = *(const float4*)(su + bn);
        const float4 nlo1 = *(const float4*)(su + bn + 4);
        const int sn = (sl + 8 < 1024) ? sl + 8 : 0;
        const float4 nk0 = *(const float4*)(kr + sn);
        const float4 nk1 = *(const float4*)(kr + sn + 4);

        const float w[16] = {lo0.x, lo0.y, lo0.z, lo0.w,
                             lo1.x, lo1.y, lo1.z, lo1.w,
                             hi0.x, hi0.y, hi0.z, hi0.w,
                             hi1.x, hi1.y, hi1.z, hi1.w};
        const float kk[8] = {k0.x, k0.y, k0.z, k0.w, k1.x, k1.y, k1.z, k1.w};
#pragma unroll
        for (int d = 0; d < 8; ++d)
#pragma unroll
            for (int r = 0; r < 8; ++r)
                ac[r] = fmaf(kk[d], w[7 + r - d], ac[r]);

        hi0 = lo0; hi1 = lo1;
        lo0 = nlo0; lo1 = nlo1;
        k0 = nk0; k1 = nk1;
        W = Wn;
    }

    if (cls == 0) {
        const float dh = dvec[h];
#pragma unroll
        for (int r = 0; r < 8; ++r)
            out[(tl + r) * H_CH + h] = fmaf(dh, su[PP(1031 + tl + r)], ac[r]);
    } else if (cls == 1) {
#pragma unroll
        for (int r = 0; r < 8; ++r) P1[(tl + r) * H_CH + h] = ac[r];
    } else {
#pragma unroll
        for (int r = 0; r < 8; ++r) P2[(tl + r) * H_CH + h] = ac[r];
    }
}

// ---------------------------------------------------------------------------
// Kernel 5: out[1024:2048] = P1 + P2 + d*u   (pure elementwise, float4)
// ---------------------------------------------------------------------------
__global__ __launch_bounds__(256)
void s4_combine(const float4* __restrict__ P1, const float4* __restrict__ P2,
                const float4* __restrict__ u4, const float4* __restrict__ d4,
                float4* __restrict__ out4)
{
    const int f = blockIdx.x * 256 + threadIdx.x;       // [0, 131072)
    const float4 a  = P1[f];
    const float4 b  = P2[f];
    const float4 uu = u4[131072 + f];                   // u rows 1024..2047
    const float4 dd = d4[f & 127];                      // dvec[h..h+3]
    out4[131072 + f] = make_float4(fmaf(dd.x, uu.x, a.x + b.x),
                                   fmaf(dd.y, uu.y, a.y + b.y),
                                   fmaf(dd.z, uu.z, a.z + b.z),
                                   fmaf(dd.w, uu.w, a.w + b.w));
}

// ---------------------------------------------------------------------------
extern "C" void kernel_launch(void* const* d_in, const int* in_sizes, int n_in,
                              void* d_out, int out_size, void* d_ws, size_t ws_size,
                              hipStream_t stream)
{
    const float* u        = (const float*)d_in[0];
    const float* lam_r    = (const float*)d_in[1];
    const float* lam_i    = (const float*)d_in[2];
    const float* p_r      = (const float*)d_in[3];
    const float* p_i      = (const float*)d_in[4];
    const float* b_r      = (const float*)d_in[5];
    const float* b_i      = (const float*)d_in[6];
    const float* cmat     = (const float*)d_in[7];
    const float* dvec     = (const float*)d_in[8];
    const float* log_step = (const float*)d_in[9];
    float* out = (float*)d_out;

    char* ws = (char*)d_ws;
    float2* roots = (float2*)ws;                              // 8 MB @ 0
    float*  kern  = (float*)ws;                               // 4 MB @ 0 (over roots; ok after pair)
    float2* X     = (float2*)(ws + (size_t)8 * 1024 * 1024);  // 4 MB @ 8M (dead after idft)
    float*  P1    = (float*)(ws + (size_t)8 * 1024 * 1024);   // 2 MB @ 8M (over X)
    float*  P2    = (float*)(ws + (size_t)10 * 1024 * 1024);  // 2 MB @ 10M
    float4* Wa    = (float4*)(ws + (size_t)12 * 1024 * 1024); // 512 KB
    float4* Wb    = (float4*)(ws + (size_t)12 * 1024 * 1024 + 512 * 1024);
    float*  Wc    = (float*) (ws + (size_t)13 * 1024 * 1024); // 128 KB

    s4_prep<<<dim3(H_CH * N_ST / 256), dim3(256), 0, stream>>>(
        lam_r, lam_i, p_r, p_i, b_r, b_i, cmat, Wa, Wb, Wc);
    s4_cauchy<<<dim3(L_SEQ / 256, H_CH), dim3(256), 0, stream>>>(
        Wa, Wb, Wc, log_step, roots);
    s4_pair<<<dim3(1024 / 256, H_CH), dim3(256), 0, stream>>>(roots, X);
    s4_idft<<<dim3(1024 / 256, H_CH), dim3(256), 0, stream>>>(X, kern);
    s4_conv<<<dim3(3, H_CH), dim3(128), 0, stream>>>(kern, u, dvec, out, P1, P2);
    s4_combine<<<dim3(512), dim3(256), 0, stream>>>(
        (const float4*)P1, (const float4*)P2, (const float4*)u,
        (const float4*)dvec, (float4*)out);
}

// Round 7
// 113.878 us; speedup vs baseline: 3.5606x; 1.5804x over previous
//
#include <hip/hip_runtime.h>
#include <math.h>

#define L_SEQ 2048
#define H_CH  512
#define N_ST  64

__device__ __forceinline__ float frcp(float x) { return __builtin_amdgcn_rcpf(x); }
// Quad-granular LDS pad for conv (float granularity)
#define PP(i) ((i) + (((i) >> 4) << 2))
// float2-granular LDS pad for fft buffers
#define A2(i) ((i) + ((i) >> 4))

// ---------------------------------------------------------------------------
// Kernel 0: precompute per-(h,n) Cauchy weights into global scratch.
// ---------------------------------------------------------------------------
__global__ __launch_bounds__(256)
void s4_prep(const float* __restrict__ lam_r_g, const float* __restrict__ lam_i_g,
             const float* __restrict__ p_r_g,  const float* __restrict__ p_i_g,
             const float* __restrict__ b_r_g,  const float* __restrict__ b_i_g,
             const float* __restrict__ c_g,
             float4* __restrict__ Wa, float4* __restrict__ Wb, float* __restrict__ Wc)
{
    const int g = blockIdx.x * 256 + threadIdx.x;      // [0, 512*64)
    const float lr = fminf(lam_r_g[g], -0.0001f);
    const float li = lam_i_g[g];
    const float pr = p_r_g[g], pi = p_i_g[g];
    const float br = b_r_g[g], bi = b_i_g[g];
    const float c0 = c_g[2 * g], c1 = c_g[2 * g + 1];
    Wa[g] = make_float4(lr, li, c0 * br + c1 * bi, c0 * bi - c1 * br);
    Wb[g] = make_float4(c0 * pr + c1 * pi, c0 * pi - c1 * pr,
                        pr * br + pi * bi, pr * bi - pi * br);
    Wc[g] = pr * pr + pi * pi;
}

// ---------------------------------------------------------------------------
// Kernel 1: Cauchy generating function -> roots[h][l] (complex)
// ---------------------------------------------------------------------------
__global__ __launch_bounds__(256)
void s4_cauchy(const float4* __restrict__ Wa, const float4* __restrict__ Wb,
               const float* __restrict__ Wc, const float* __restrict__ log_step_g,
               float2* __restrict__ roots)
{
    const int h = blockIdx.y;
    const int l = blockIdx.x * 256 + threadIdx.x;

    const float step = expf(log_step_g[h]);
    const float ts   = 2.0f / step;

    const float ang = -6.2831853071795864769f * ((float)l * (1.0f / (float)L_SEQ));
    float wi, wr;
    sincosf(ang, &wi, &wr);                      // omega = (wr, wi)

    const float dr = 1.0f + wr, di = wi;         // 1 + omega
    const float dinv = frcp(dr * dr + di * di);
    const float nr = 1.0f - wr, ni = -wi;        // 1 - omega
    const float gr = ts * (nr * dr + ni * di) * dinv;
    const float gi = ts * (ni * dr - nr * di) * dinv;
    const float c2r = 2.0f * dr * dinv;
    const float c2i = -2.0f * di * dinv;

    const float4* __restrict__ wa = Wa + h * N_ST;
    const float4* __restrict__ wb = Wb + h * N_ST;
    const float*  __restrict__ wc = Wc + h * N_ST;

    float k00r = 0.f, k00i = 0.f, k01r = 0.f, k01i = 0.f;
    float k10r = 0.f, k10i = 0.f, k11r = 0.f, k11i = 0.f;
#pragma unroll 4
    for (int n = 0; n < N_ST; ++n) {
        const float4 A = wa[n];
        const float4 B = wb[n];
        const float w11 = wc[n];
        const float ddr = gr - A.x;
        const float ddi = gi - A.y;
        const float rinv = frcp(fmaf(ddr, ddr, ddi * ddi));
        const float rr = ddr * rinv;
        const float ri = -ddi * rinv;
        k00r = fmaf(A.z, rr, fmaf(-A.w, ri, k00r));
        k00i = fmaf(A.z, ri, fmaf( A.w, rr, k00i));
        k01r = fmaf(B.x, rr, fmaf(-B.y, ri, k01r));
        k01i = fmaf(B.x, ri, fmaf( B.y, rr, k01i));
        k10r = fmaf(B.z, rr, fmaf(-B.w, ri, k10r));
        k10i = fmaf(B.z, ri, fmaf( B.w, rr, k10i));
        k11r = fmaf(w11, rr, k11r);
        k11i = fmaf(w11, ri, k11i);
    }

    const float qdr = 1.0f + k11r, qdi = k11i;
    const float qinv = frcp(qdr * qdr + qdi * qdi);
    const float pnr = k01r * k10r - k01i * k10i;
    const float pni = k01r * k10i + k01i * k10r;
    const float qr = (pnr * qdr + pni * qdi) * qinv;
    const float qi = (pni * qdr - pnr * qdi) * qinv;
    const float rr0 = k00r - qr;
    const float ri0 = k00i - qi;
    roots[h * L_SEQ + l] = make_float2(c2r * rr0 - c2i * ri0,
                                       c2r * ri0 + c2i * rr0);
}

// ---------------------------------------------------------------------------
// Kernel 2: kern[h] = Re(ifft_2048(roots[h])) via Hermitian-symmetrized irfft:
//   Xs[m] = (roots[m] + conj(roots[2048-m]))/2  (so Re(ifft(roots)) == irfft(Xs))
//   Zf[k] = (Xs[k]+conj(Xs[1024-k])) + i e^{2pi i k/2048}(Xs[k]-conj(Xs[1024-k]))
//   z = (1/2048) * IDFTsum_1024(Zf);  kern[2n]=Re z[n], kern[2n+1]=Im z[n]
// IDFT by radix-2 DIF in LDS (natural in, bit-reversed out; resolved at read).
// ---------------------------------------------------------------------------
__global__ __launch_bounds__(256)
void s4_ifft(const float2* __restrict__ roots, float2* __restrict__ kern2)
{
    __shared__ float2 buf[1088];   // A2(1023)=1086
    __shared__ float2 tw[544];     // A2(511)=542, tw[k]=e^{+2pi i k/1024}
    const int h   = blockIdx.x;
    const int tid = threadIdx.x;
    const float2* __restrict__ r = roots + h * L_SEQ;

    for (int k = tid; k < 512; k += 256) {
        float sv, cv;
        sincosf((float)k * (6.2831853071795864769f / 1024.0f), &sv, &cv);
        tw[A2(k)] = make_float2(cv, sv);
    }

#pragma unroll
    for (int q = 0; q < 4; ++q) {
        const int k = tid + q * 256;
        float zr, zi;
        if (k == 0) {
            const float X0 = r[0].x, XM = r[1024].x;
            zr = X0 + XM;  zi = X0 - XM;
        } else {
            const float2 a  = r[k],        b2 = r[2048 - k];
            const float2 a2 = r[1024 - k], b3 = r[1024 + k];
            const float xkr = 0.5f * (a.x + b2.x),  xki = 0.5f * (a.y - b2.y);
            const float xmr = 0.5f * (a2.x + b3.x), xmi = -0.5f * (a2.y - b3.y);
            const float er = xkr + xmr, ei = xki + xmi;
            const float o_r = xkr - xmr, o_i = xki - xmi;
            float sv, cv;
            sincosf((float)k * (6.2831853071795864769f / 2048.0f), &sv, &cv);
            zr = er - fmaf(cv, o_i,  sv * o_r);
            zi = ei + fmaf(cv, o_r, -sv * o_i);
        }
        buf[A2(k)] = make_float2(zr, zi);
    }
    __syncthreads();

#pragma unroll
    for (int st = 0; st < 10; ++st) {
        const int h2s = 512 >> st;              // half butterfly span
#pragma unroll
        for (int bq = 0; bq < 2; ++bq) {
            const int b  = tid + bq * 256;      // butterfly id [0,512)
            const int j  = b & (h2s - 1);
            const int i0 = ((b >> (9 - st)) << (10 - st)) + j;
            const int i1 = i0 + h2s;
            const float2 u = buf[A2(i0)];
            const float2 v = buf[A2(i1)];
            const float2 w = tw[A2(j << st)];   // e^{+2pi i j/len}
            buf[A2(i0)] = make_float2(u.x + v.x, u.y + v.y);
            const float d0 = u.x - v.x, d1 = u.y - v.y;
            buf[A2(i1)] = make_float2(d0 * w.x - d1 * w.y, d0 * w.y + d1 * w.x);
        }
        __syncthreads();
    }

#pragma unroll
    for (int q = 0; q < 4; ++q) {
        const int n  = tid + q * 256;
        const int br = __brev(n) >> 22;         // 10-bit reversal
        const float2 z = buf[A2(br)];
        kern2[h * 1024 + n] = make_float2(z.x * (1.0f / 2048.0f),
                                          z.y * (1.0f / 2048.0f));
    }
}

// ---------------------------------------------------------------------------
// Kernel 4: causal conv, 3 identical-shape block classes per h (as R6).
// ---------------------------------------------------------------------------
__global__ __launch_bounds__(128)
void s4_conv(const float* __restrict__ kern, const float* __restrict__ u,
             const float* __restrict__ dvec, float* __restrict__ out,
             float* __restrict__ P1, float* __restrict__ P2)
{
    __shared__ __align__(16) float su[2576];   // PP(2055)=2567 max
    const int cls = blockIdx.x;                // 0,1,2
    const int h   = blockIdx.y;
    const int tid = threadIdx.x;               // [0,128)
    const int tl  = tid * 8;                   // local output base

    for (int i = tid; i < 2576; i += 128) su[i] = 0.0f;
    __syncthreads();
    if (cls == 1) {
        for (int j = tid; j < 2048; j += 128) su[PP(7 + j)] = u[j * H_CH + h];
    } else {
        for (int j = tid; j < 1024; j += 128) su[PP(1031 + j)] = u[j * H_CH + h];
    }
    __syncthreads();

    const float* __restrict__ kr = kern + h * L_SEQ + (cls == 2 ? 1024 : 0);

    float ac[8];
#pragma unroll
    for (int r = 0; r < 8; ++r) ac[r] = 0.0f;

    int W = tl + 1024;
    int bh = PP(W + 8), bl = PP(W);
    float4 hi0 = *(const float4*)(su + bh);
    float4 hi1 = *(const float4*)(su + bh + 4);
    float4 lo0 = *(const float4*)(su + bl);
    float4 lo1 = *(const float4*)(su + bl + 4);
    float4 k0  = *(const float4*)(kr);
    float4 k1  = *(const float4*)(kr + 4);

    for (int sl = 0; sl < 1024; sl += 8) {
        const int Wn = W - 8;
        const int bn = PP(Wn);
        const float4 nlo0 = *(const float4*)(su + bn);
        const float4 nlo1 = *(const float4*)(su + bn + 4);
        const int sn = (sl + 8 < 1024) ? sl + 8 : 0;
        const float4 nk0 = *(const float4*)(kr + sn);
        const float4 nk1 = *(const float4*)(kr + sn + 4);

        const float w[16] = {lo0.x, lo0.y, lo0.z, lo0.w,
                             lo1.x, lo1.y, lo1.z, lo1.w,
                             hi0.x, hi0.y, hi0.z, hi0.w,
                             hi1.x, hi1.y, hi1.z, hi1.w};
        const float kk[8] = {k0.x, k0.y, k0.z, k0.w, k1.x, k1.y, k1.z, k1.w};
#pragma unroll
        for (int d = 0; d < 8; ++d)
#pragma unroll
            for (int r = 0; r < 8; ++r)
                ac[r] = fmaf(kk[d], w[7 + r - d], ac[r]);

        hi0 = lo0; hi1 = lo1;
        lo0 = nlo0; lo1 = nlo1;
        k0 = nk0; k1 = nk1;
        W = Wn;
    }

    if (cls == 0) {
        const float dh = dvec[h];
#pragma unroll
        for (int r = 0; r < 8; ++r)
            out[(tl + r) * H_CH + h] = fmaf(dh, su[PP(1031 + tl + r)], ac[r]);
    } else if (cls == 1) {
#pragma unroll
        for (int r = 0; r < 8; ++r) P1[(tl + r) * H_CH + h] = ac[r];
    } else {
#pragma unroll
        for (int r = 0; r < 8; ++r) P2[(tl + r) * H_CH + h] = ac[r];
    }
}

// ---------------------------------------------------------------------------
// Kernel 5: out[1024:2048] = P1 + P2 + d*u
// ---------------------------------------------------------------------------
__global__ __launch_bounds__(256)
void s4_combine(const float4* __restrict__ P1, const float4* __restrict__ P2,
                const float4* __restrict__ u4, const float4* __restrict__ d4,
                float4* __restrict__ out4)
{
    const int f = blockIdx.x * 256 + threadIdx.x;       // [0, 131072)
    const float4 a  = P1[f];
    const float4 b  = P2[f];
    const float4 uu = u4[131072 + f];
    const float4 dd = d4[f & 127];
    out4[131072 + f] = make_float4(fmaf(dd.x, uu.x, a.x + b.x),
                                   fmaf(dd.y, uu.y, a.y + b.y),
                                   fmaf(dd.z, uu.z, a.z + b.z),
                                   fmaf(dd.w, uu.w, a.w + b.w));
}

// ---------------------------------------------------------------------------
extern "C" void kernel_launch(void* const* d_in, const int* in_sizes, int n_in,
                              void* d_out, int out_size, void* d_ws, size_t ws_size,
                              hipStream_t stream)
{
    const float* u        = (const float*)d_in[0];
    const float* lam_r    = (const float*)d_in[1];
    const float* lam_i    = (const float*)d_in[2];
    const float* p_r      = (const float*)d_in[3];
    const float* p_i      = (const float*)d_in[4];
    const float* b_r      = (const float*)d_in[5];
    const float* b_i      = (const float*)d_in[6];
    const float* cmat     = (const float*)d_in[7];
    const float* dvec     = (const float*)d_in[8];
    const float* log_step = (const float*)d_in[9];
    float* out = (float*)d_out;

    char* ws = (char*)d_ws;
    float2* roots = (float2*)ws;                              // 8 MB @ 0 (dead after ifft)
    float*  kern  = (float*)(ws + (size_t)8 * 1024 * 1024);   // 4 MB @ 8M
    float*  P1    = (float*)ws;                               // 2 MB @ 0  (over roots)
    float*  P2    = (float*)(ws + (size_t)2 * 1024 * 1024);   // 2 MB @ 2M (over roots)
    float4* Wa    = (float4*)(ws + (size_t)12 * 1024 * 1024); // 512 KB
    float4* Wb    = (float4*)(ws + (size_t)12 * 1024 * 1024 + 512 * 1024);
    float*  Wc    = (float*) (ws + (size_t)13 * 1024 * 1024); // 128 KB

    s4_prep<<<dim3(H_CH * N_ST / 256), dim3(256), 0, stream>>>(
        lam_r, lam_i, p_r, p_i, b_r, b_i, cmat, Wa, Wb, Wc);
    s4_cauchy<<<dim3(L_SEQ / 256, H_CH), dim3(256), 0, stream>>>(
        Wa, Wb, Wc, log_step, roots);
    s4_ifft<<<dim3(H_CH), dim3(256), 0, stream>>>(roots, (float2*)kern);
    s4_conv<<<dim3(3, H_CH), dim3(128), 0, stream>>>(kern, u, dvec, out, P1, P2);
    s4_combine<<<dim3(512), dim3(256), 0, stream>>>(
        (const float4*)P1, (const float4*)P2, (const float4*)u,
        (const float4*)dvec, (float4*)out);
}

// Round 8
// 111.959 us; speedup vs baseline: 3.6216x; 1.0171x over previous
//
#include <hip/hip_runtime.h>
#include <math.h>

#define L_SEQ 2048
#define H_CH  512
#define N_ST  64

__device__ __forceinline__ float frcp(float x) { return __builtin_amdgcn_rcpf(x); }
// Quad-granular LDS pad for conv (float granularity)
#define PP(i) ((i) + (((i) >> 4) << 2))
// float2-granular LDS pad for fft buffers
#define A2(i) ((i) + ((i) >> 4))

// ---------------------------------------------------------------------------
// Kernel 0: precompute per-(h,n) Cauchy weights into global scratch.
// ---------------------------------------------------------------------------
__global__ __launch_bounds__(256)
void s4_prep(const float* __restrict__ lam_r_g, const float* __restrict__ lam_i_g,
             const float* __restrict__ p_r_g,  const float* __restrict__ p_i_g,
             const float* __restrict__ b_r_g,  const float* __restrict__ b_i_g,
             const float* __restrict__ c_g,
             float4* __restrict__ Wa, float4* __restrict__ Wb, float* __restrict__ Wc)
{
    const int g = blockIdx.x * 256 + threadIdx.x;      // [0, 512*64)
    const float lr = fminf(lam_r_g[g], -0.0001f);
    const float li = lam_i_g[g];
    const float pr = p_r_g[g], pi = p_i_g[g];
    const float br = b_r_g[g], bi = b_i_g[g];
    const float c0 = c_g[2 * g], c1 = c_g[2 * g + 1];
    Wa[g] = make_float4(lr, li, c0 * br + c1 * bi, c0 * bi - c1 * br);
    Wb[g] = make_float4(c0 * pr + c1 * pi, c0 * pi - c1 * pr,
                        pr * br + pi * bi, pr * bi - pi * br);
    Wc[g] = pr * pr + pi * pi;
}

// ---------------------------------------------------------------------------
// Kernel 1: Cauchy generating function -> roots[h][l] (complex)
// ---------------------------------------------------------------------------
__global__ __launch_bounds__(256)
void s4_cauchy(const float4* __restrict__ Wa, const float4* __restrict__ Wb,
               const float* __restrict__ Wc, const float* __restrict__ log_step_g,
               float2* __restrict__ roots)
{
    const int h = blockIdx.y;
    const int l = blockIdx.x * 256 + threadIdx.x;

    const float step = expf(log_step_g[h]);
    const float ts   = 2.0f / step;

    const float ang = -6.2831853071795864769f * ((float)l * (1.0f / (float)L_SEQ));
    float wi, wr;
    sincosf(ang, &wi, &wr);                      // omega = (wr, wi)

    const float dr = 1.0f + wr, di = wi;         // 1 + omega
    const float dinv = frcp(dr * dr + di * di);
    const float nr = 1.0f - wr, ni = -wi;        // 1 - omega
    const float gr = ts * (nr * dr + ni * di) * dinv;
    const float gi = ts * (ni * dr - nr * di) * dinv;
    const float c2r = 2.0f * dr * dinv;
    const float c2i = -2.0f * di * dinv;

    const float4* __restrict__ wa = Wa + h * N_ST;
    const float4* __restrict__ wb = Wb + h * N_ST;
    const float*  __restrict__ wc = Wc + h * N_ST;

    float k00r = 0.f, k00i = 0.f, k01r = 0.f, k01i = 0.f;
    float k10r = 0.f, k10i = 0.f, k11r = 0.f, k11i = 0.f;
#pragma unroll 4
    for (int n = 0; n < N_ST; ++n) {
        const float4 A = wa[n];
        const float4 B = wb[n];
        const float w11 = wc[n];
        const float ddr = gr - A.x;
        const float ddi = gi - A.y;
        const float rinv = frcp(fmaf(ddr, ddr, ddi * ddi));
        const float rr = ddr * rinv;
        const float ri = -ddi * rinv;
        k00r = fmaf(A.z, rr, fmaf(-A.w, ri, k00r));
        k00i = fmaf(A.z, ri, fmaf( A.w, rr, k00i));
        k01r = fmaf(B.x, rr, fmaf(-B.y, ri, k01r));
        k01i = fmaf(B.x, ri, fmaf( B.y, rr, k01i));
        k10r = fmaf(B.z, rr, fmaf(-B.w, ri, k10r));
        k10i = fmaf(B.z, ri, fmaf( B.w, rr, k10i));
        k11r = fmaf(w11, rr, k11r);
        k11i = fmaf(w11, ri, k11i);
    }

    const float qdr = 1.0f + k11r, qdi = k11i;
    const float qinv = frcp(qdr * qdr + qdi * qdi);
    const float pnr = k01r * k10r - k01i * k10i;
    const float pni = k01r * k10i + k01i * k10r;
    const float qr = (pnr * qdr + pni * qdi) * qinv;
    const float qi = (pni * qdr - pnr * qdi) * qinv;
    const float rr0 = k00r - qr;
    const float ri0 = k00i - qi;
    roots[h * L_SEQ + l] = make_float2(c2r * rr0 - c2i * ri0,
                                       c2r * ri0 + c2i * rr0);
}

// ---------------------------------------------------------------------------
// Kernel 2: kern[h] = Re(ifft_2048(roots[h])) via half-size complex iFFT (R7).
// ---------------------------------------------------------------------------
__global__ __launch_bounds__(256)
void s4_ifft(const float2* __restrict__ roots, float2* __restrict__ kern2)
{
    __shared__ float2 buf[1088];   // A2(1023)=1086
    __shared__ float2 tw[544];     // A2(511)=542, tw[k]=e^{+2pi i k/1024}
    const int h   = blockIdx.x;
    const int tid = threadIdx.x;
    const float2* __restrict__ r = roots + h * L_SEQ;

    for (int k = tid; k < 512; k += 256) {
        float sv, cv;
        sincosf((float)k * (6.2831853071795864769f / 1024.0f), &sv, &cv);
        tw[A2(k)] = make_float2(cv, sv);
    }

#pragma unroll
    for (int q = 0; q < 4; ++q) {
        const int k = tid + q * 256;
        float zr, zi;
        if (k == 0) {
            const float X0 = r[0].x, XM = r[1024].x;
            zr = X0 + XM;  zi = X0 - XM;
        } else {
            const float2 a  = r[k],        b2 = r[2048 - k];
            const float2 a2 = r[1024 - k], b3 = r[1024 + k];
            const float xkr = 0.5f * (a.x + b2.x),  xki = 0.5f * (a.y - b2.y);
            const float xmr = 0.5f * (a2.x + b3.x), xmi = -0.5f * (a2.y - b3.y);
            const float er = xkr + xmr, ei = xki + xmi;
            const float o_r = xkr - xmr, o_i = xki - xmi;
            float sv, cv;
            sincosf((float)k * (6.2831853071795864769f / 2048.0f), &sv, &cv);
            zr = er - fmaf(cv, o_i,  sv * o_r);
            zi = ei + fmaf(cv, o_r, -sv * o_i);
        }
        buf[A2(k)] = make_float2(zr, zi);
    }
    __syncthreads();

#pragma unroll
    for (int st = 0; st < 10; ++st) {
        const int h2s = 512 >> st;              // half butterfly span
#pragma unroll
        for (int bq = 0; bq < 2; ++bq) {
            const int b  = tid + bq * 256;      // butterfly id [0,512)
            const int j  = b & (h2s - 1);
            const int i0 = ((b >> (9 - st)) << (10 - st)) + j;
            const int i1 = i0 + h2s;
            const float2 u = buf[A2(i0)];
            const float2 v = buf[A2(i1)];
            const float2 w = tw[A2(j << st)];   // e^{+2pi i j/len}
            buf[A2(i0)] = make_float2(u.x + v.x, u.y + v.y);
            const float d0 = u.x - v.x, d1 = u.y - v.y;
            buf[A2(i1)] = make_float2(d0 * w.x - d1 * w.y, d0 * w.y + d1 * w.x);
        }
        __syncthreads();
    }

#pragma unroll
    for (int q = 0; q < 4; ++q) {
        const int n  = tid + q * 256;
        const int br = __brev(n) >> 22;         // 10-bit reversal
        const float2 z = buf[A2(br)];
        kern2[h * 1024 + n] = make_float2(z.x * (1.0f / 2048.0f),
                                          z.y * (1.0f / 2048.0f));
    }
}

// ---------------------------------------------------------------------------
// Kernel 4: causal conv, 3 identical-shape block classes per h.
// Fully scalarized inner loop: named float4 window regs, period-4 rotation
// (A,B,C,D), 64 explicit fmafs per 8-tap chunk. No local arrays -> compiler
// cannot demote the window to LDS re-reads (R7: VGPR=24 pathology).
// ---------------------------------------------------------------------------
// taps ka/kb multiply window regs L0,L1,H0,H1 (= su[W..W+15]); row r uses
// w[7+r-d], w0..w3=L0.xyzw, w4..w7=L1.xyzw, w8..w11=H0.xyzw, w12..w14=H1.xyz
#define CONV8(L0,L1,H0,H1,TAPS) do {                                          \
    const float4 ka = *(const float4*)(kr + (TAPS));                          \
    const float4 kb = *(const float4*)(kr + (TAPS) + 4);                      \
    ac0=fmaf(ka.x,L1.w,ac0); ac0=fmaf(ka.y,L1.z,ac0); ac0=fmaf(ka.z,L1.y,ac0); ac0=fmaf(ka.w,L1.x,ac0); \
    ac0=fmaf(kb.x,L0.w,ac0); ac0=fmaf(kb.y,L0.z,ac0); ac0=fmaf(kb.z,L0.y,ac0); ac0=fmaf(kb.w,L0.x,ac0); \
    ac1=fmaf(ka.x,H0.x,ac1); ac1=fmaf(ka.y,L1.w,ac1); ac1=fmaf(ka.z,L1.z,ac1); ac1=fmaf(ka.w,L1.y,ac1); \
    ac1=fmaf(kb.x,L1.x,ac1); ac1=fmaf(kb.y,L0.w,ac1); ac1=fmaf(kb.z,L0.z,ac1); ac1=fmaf(kb.w,L0.y,ac1); \
    ac2=fmaf(ka.x,H0.y,ac2); ac2=fmaf(ka.y,H0.x,ac2); ac2=fmaf(ka.z,L1.w,ac2); ac2=fmaf(ka.w,L1.z,ac2); \
    ac2=fmaf(kb.x,L1.y,ac2); ac2=fmaf(kb.y,L1.x,ac2); ac2=fmaf(kb.z,L0.w,ac2); ac2=fmaf(kb.w,L0.z,ac2); \
    ac3=fmaf(ka.x,H0.z,ac3); ac3=fmaf(ka.y,H0.y,ac3); ac3=fmaf(ka.z,H0.x,ac3); ac3=fmaf(ka.w,L1.w,ac3); \
    ac3=fmaf(kb.x,L1.z,ac3); ac3=fmaf(kb.y,L1.y,ac3); ac3=fmaf(kb.z,L1.x,ac3); ac3=fmaf(kb.w,L0.w,ac3); \
    ac4=fmaf(ka.x,H0.w,ac4); ac4=fmaf(ka.y,H0.z,ac4); ac4=fmaf(ka.z,H0.y,ac4); ac4=fmaf(ka.w,H0.x,ac4); \
    ac4=fmaf(kb.x,L1.w,ac4); ac4=fmaf(kb.y,L1.z,ac4); ac4=fmaf(kb.z,L1.y,ac4); ac4=fmaf(kb.w,L1.x,ac4); \
    ac5=fmaf(ka.x,H1.x,ac5); ac5=fmaf(ka.y,H0.w,ac5); ac5=fmaf(ka.z,H0.z,ac5); ac5=fmaf(ka.w,H0.y,ac5); \
    ac5=fmaf(kb.x,H0.x,ac5); ac5=fmaf(kb.y,L1.w,ac5); ac5=fmaf(kb.z,L1.z,ac5); ac5=fmaf(kb.w,L1.y,ac5); \
    ac6=fmaf(ka.x,H1.y,ac6); ac6=fmaf(ka.y,H1.x,ac6); ac6=fmaf(ka.z,H0.w,ac6); ac6=fmaf(ka.w,H0.z,ac6); \
    ac6=fmaf(kb.x,H0.y,ac6); ac6=fmaf(kb.y,H0.x,ac6); ac6=fmaf(kb.z,L1.w,ac6); ac6=fmaf(kb.w,L1.z,ac6); \
    ac7=fmaf(ka.x,H1.z,ac7); ac7=fmaf(ka.y,H1.y,ac7); ac7=fmaf(ka.z,H1.x,ac7); ac7=fmaf(ka.w,H0.w,ac7); \
    ac7=fmaf(kb.x,H0.z,ac7); ac7=fmaf(kb.y,H0.y,ac7); ac7=fmaf(kb.z,H0.x,ac7); ac7=fmaf(kb.w,L1.w,ac7); \
} while (0)

#define LDPAIR(P0,P1,IDX) do { const int _b = PP(IDX);                        \
    P0 = *(const float4*)(su + _b); P1 = *(const float4*)(su + _b + 4); } while (0)

__global__ __launch_bounds__(128)
void s4_conv(const float* __restrict__ kern, const float* __restrict__ u,
             const float* __restrict__ dvec, float* __restrict__ out,
             float* __restrict__ P1, float* __restrict__ P2)
{
    __shared__ __align__(16) float su[2576];   // PP(2055)=2567 max
    const int cls = blockIdx.x;                // 0,1,2
    const int h   = blockIdx.y;
    const int tid = threadIdx.x;               // [0,128)
    const int tl  = tid * 8;                   // local output base

    for (int i = tid; i < 2576; i += 128) su[i] = 0.0f;
    __syncthreads();
    if (cls == 1) {
        for (int j = tid; j < 2048; j += 128) su[PP(7 + j)] = u[j * H_CH + h];
    } else {
        for (int j = tid; j < 1024; j += 128) su[PP(1031 + j)] = u[j * H_CH + h];
    }
    __syncthreads();

    const float* __restrict__ kr = kern + h * L_SEQ + (cls == 2 ? 1024 : 0);

    float ac0 = 0.f, ac1 = 0.f, ac2 = 0.f, ac3 = 0.f;
    float ac4 = 0.f, ac5 = 0.f, ac6 = 0.f, ac7 = 0.f;

    float4 A0, A1, B0, B1, C0, C1, D0, D1;
    int W = tl + 1024;                         // window base (logical su index)
    LDPAIR(A0, A1, W);                         // lo
    LDPAIR(B0, B1, W + 8);                     // hi

    for (int it = 0; it < 32; ++it) {
        const int s0 = it << 5;
        LDPAIR(C0, C1, W - 8);
        CONV8(A0, A1, B0, B1, s0);
        LDPAIR(D0, D1, W - 16);
        CONV8(C0, C1, A0, A1, s0 + 8);
        LDPAIR(B0, B1, W - 24);
        CONV8(D0, D1, C0, C1, s0 + 16);
        LDPAIR(A0, A1, W - 32);
        CONV8(B0, B1, D0, D1, s0 + 24);
        W -= 32;
    }

    if (cls == 0) {
        const float dh = dvec[h];
        out[(tl + 0) * H_CH + h] = fmaf(dh, su[PP(1031 + tl + 0)], ac0);
        out[(tl + 1) * H_CH + h] = fmaf(dh, su[PP(1031 + tl + 1)], ac1);
        out[(tl + 2) * H_CH + h] = fmaf(dh, su[PP(1031 + tl + 2)], ac2);
        out[(tl + 3) * H_CH + h] = fmaf(dh, su[PP(1031 + tl + 3)], ac3);
        out[(tl + 4) * H_CH + h] = fmaf(dh, su[PP(1031 + tl + 4)], ac4);
        out[(tl + 5) * H_CH + h] = fmaf(dh, su[PP(1031 + tl + 5)], ac5);
        out[(tl + 6) * H_CH + h] = fmaf(dh, su[PP(1031 + tl + 6)], ac6);
        out[(tl + 7) * H_CH + h] = fmaf(dh, su[PP(1031 + tl + 7)], ac7);
    } else {
        float* __restrict__ dst = (cls == 1) ? P1 : P2;
        dst[(tl + 0) * H_CH + h] = ac0;
        dst[(tl + 1) * H_CH + h] = ac1;
        dst[(tl + 2) * H_CH + h] = ac2;
        dst[(tl + 3) * H_CH + h] = ac3;
        dst[(tl + 4) * H_CH + h] = ac4;
        dst[(tl + 5) * H_CH + h] = ac5;
        dst[(tl + 6) * H_CH + h] = ac6;
        dst[(tl + 7) * H_CH + h] = ac7;
    }
}

// ---------------------------------------------------------------------------
// Kernel 5: out[1024:2048] = P1 + P2 + d*u
// ---------------------------------------------------------------------------
__global__ __launch_bounds__(256)
void s4_combine(const float4* __restrict__ P1, const float4* __restrict__ P2,
                const float4* __restrict__ u4, const float4* __restrict__ d4,
                float4* __restrict__ out4)
{
    const int f = blockIdx.x * 256 + threadIdx.x;       // [0, 131072)
    const float4 a  = P1[f];
    const float4 b  = P2[f];
    const float4 uu = u4[131072 + f];
    const float4 dd = d4[f & 127];
    out4[131072 + f] = make_float4(fmaf(dd.x, uu.x, a.x + b.x),
                                   fmaf(dd.y, uu.y, a.y + b.y),
                                   fmaf(dd.z, uu.z, a.z + b.z),
                                   fmaf(dd.w, uu.w, a.w + b.w));
}

// ---------------------------------------------------------------------------
extern "C" void kernel_launch(void* const* d_in, const int* in_sizes, int n_in,
                              void* d_out, int out_size, void* d_ws, size_t ws_size,
                              hipStream_t stream)
{
    const float* u        = (const float*)d_in[0];
    const float* lam_r    = (const float*)d_in[1];
    const float* lam_i    = (const float*)d_in[2];
    const float* p_r      = (const float*)d_in[3];
    const float* p_i      = (const float*)d_in[4];
    const float* b_r      = (const float*)d_in[5];
    const float* b_i      = (const float*)d_in[6];
    const float* cmat     = (const float*)d_in[7];
    const float* dvec     = (const float*)d_in[8];
    const float* log_step = (const float*)d_in[9];
    float* out = (float*)d_out;

    char* ws = (char*)d_ws;
    float2* roots = (float2*)ws;                              // 8 MB @ 0 (dead after ifft)
    float*  kern  = (float*)(ws + (size_t)8 * 1024 * 1024);   // 4 MB @ 8M
    float*  P1v   = (float*)ws;                               // 2 MB @ 0  (over roots)
    float*  P2v   = (float*)(ws + (size_t)2 * 1024 * 1024);   // 2 MB @ 2M (over roots)
    float4* Wa    = (float4*)(ws + (size_t)12 * 1024 * 1024); // 512 KB
    float4* Wb    = (float4*)(ws + (size_t)12 * 1024 * 1024 + 512 * 1024);
    float*  Wc    = (float*) (ws + (size_t)13 * 1024 * 1024); // 128 KB

    s4_prep<<<dim3(H_CH * N_ST / 256), dim3(256), 0, stream>>>(
        lam_r, lam_i, p_r, p_i, b_r, b_i, cmat, Wa, Wb, Wc);
    s4_cauchy<<<dim3(L_SEQ / 256, H_CH), dim3(256), 0, stream>>>(
        Wa, Wb, Wc, log_step, roots);
    s4_ifft<<<dim3(H_CH), dim3(256), 0, stream>>>(roots, (float2*)kern);
    s4_conv<<<dim3(3, H_CH), dim3(128), 0, stream>>>(kern, u, dvec, out, P1v, P2v);
    s4_combine<<<dim3(512), dim3(256), 0, stream>>>(
        (const float4*)P1v, (const float4*)P2v, (const float4*)u,
        (const float4*)dvec, (float4*)out);
}